// Round 6
// baseline (229.337 us; speedup 1.0000x reference)
//
#include <hip/hip_runtime.h>
#include <math.h>

// NSVQ: N=131072 rows, D=64, K=1024 codes (fp32).
// out (flat f32): [0,N*D) quantized; [N*D] perplexity; [N*D+1,+K) counts.
// ws layout:
//   [0,4096)         cn4k   f32[K]     4096*(||c||^2 + 512)
//   [4096,8192)      counts int[K]
//   [8192,532480)    best   uint[N]    bit31=flag, bits10..19=k2, bits0..9=k1
//   [532480,663552)  cbh    ushort[K*64] bf16 hi, swizzled 16B blocks
//   [663552,794624)  cbl    ushort[K*64] bf16 lo, swizzled 16B blocks

#define NSVQ_D 64
#define ABN 256      // rows per argmin block (512 thr, 8 waves x 32 rows -> grid 512, 2 blocks/CU)
#define THR_Q 100u   // flag threshold in 1/4096 score quanta (~0.024)

typedef __attribute__((ext_vector_type(8))) short short8;
typedef __attribute__((ext_vector_type(4))) float f32x4;

__device__ __forceinline__ ushort bftrunc(float f) {
  return (ushort)(__float_as_uint(f) >> 16);
}
__device__ __forceinline__ float bf2f(ushort h) {
  return __uint_as_float(((uint)h) << 16);
}

// ---------------- prep: codebook norms + bf16 hi/lo split (swizzled) + zero counts ----------------
__global__ __launch_bounds__(256)
void nsvq_prep(const float* __restrict__ cb,
               ushort* __restrict__ cbh, ushort* __restrict__ cbl,
               float* __restrict__ cn4k, int* __restrict__ counts, int K) {
  if (blockIdx.x == 0) ((int4*)counts)[threadIdx.x] = make_int4(0, 0, 0, 0);
  int r = blockIdx.x * 256 + threadIdx.x;  // one code per thread
  if (r >= K) return;
  const float* row = cb + (long)r * NSVQ_D;
  float nrm = 0.f;
#pragma unroll
  for (int j = 0; j < 8; ++j) {            // dim block j = dims 8j..8j+7
    float4 v0 = *(const float4*)(row + j * 8);
    float4 v1 = *(const float4*)(row + j * 8 + 4);
    float f[8] = {v0.x, v0.y, v0.z, v0.w, v1.x, v1.y, v1.z, v1.w};
    ushort h[8], l[8];
#pragma unroll
    for (int e = 0; e < 8; ++e) {
      nrm = fmaf(f[e], f[e], nrm);
      ushort hb = bftrunc(f[e]);
      h[e] = hb;
      l[e] = bftrunc(f[e] - bf2f(hb));
    }
    int blk = r * 8 + (j ^ (r & 7));       // swizzled 16B block index
    *(uint4*)(cbh + blk * 8) = *(uint4*)h;
    *(uint4*)(cbl + blk * 8) = *(uint4*)l;
  }
  cn4k[r] = 4096.f * (nrm + 512.f);        // offset keeps scores in (0, 2^22)
}

// ---------------- MFMA argmin: 256 rows/block, 8 waves, fixed-point packed top-2 ----------------
__global__ __launch_bounds__(512, 4)
void nsvq_argmin_mfma(const float* __restrict__ x,
                      const ushort* __restrict__ cbh,
                      const ushort* __restrict__ cbl,
                      const float* __restrict__ cn4k,
                      uint* __restrict__ best) {
  __shared__ ushort CS[2][2][128 * 64];    // [buf][hi/lo][code*64], 64 KB, swizzled
  __shared__ float CN[1024];               // 4 KB: cn4k resident in LDS
  const int tid = threadIdx.x;
  const int lane = tid & 63;
  const int wid = tid >> 6;                // 0..7, each wave owns 32 rows
  const int l15 = lane & 15;
  const int lg = lane >> 4;                // 0..3
  const long brow = (long)blockIdx.x * ABN;
  const int wrow = wid * 32;

  CN[tid] = cn4k[tid];
  CN[tid + 512] = cn4k[tid + 512];

  // ---- A fragments (X rows scaled by 4096), bf16 hi/lo, register-resident ----
  short8 ah[2][2], al[2][2];
#pragma unroll
  for (int rt = 0; rt < 2; ++rt) {
#pragma unroll
    for (int kk = 0; kk < 2; ++kk) {
      const float* xr = x + (brow + wrow + rt * 16 + l15) * NSVQ_D + kk * 32 + lg * 8;
      float4 v0 = *(const float4*)xr;
      float4 v1 = *(const float4*)(xr + 4);
      float f[8] = {v0.x, v0.y, v0.z, v0.w, v1.x, v1.y, v1.z, v1.w};
      short8 h, lo;
#pragma unroll
      for (int j = 0; j < 8; ++j) {
        float fs = f[j] * 4096.f;          // exact power-of-2 scale
        ushort hb = bftrunc(fs);
        h[j] = (short)hb;
        lo[j] = (short)bftrunc(fs - bf2f(hb));
      }
      ah[rt][kk] = h;
      al[rt][kk] = lo;
    }
  }

  // ---- linear chunk staging (pre-swizzled in ws): 32 KB per chunk ----
  uint4 st[4];
  auto stage_load = [&](int c) {
    const uint4* ph = (const uint4*)cbh + c * 1024;
    const uint4* pl = (const uint4*)cbl + c * 1024;
    st[0] = ph[tid];
    st[1] = ph[tid + 512];
    st[2] = pl[tid];
    st[3] = pl[tid + 512];
  };
  auto stage_write = [&](int b) {
    uint4* dh = (uint4*)&CS[b][0][0];
    uint4* dl = (uint4*)&CS[b][1][0];
    dh[tid] = st[0];
    dh[tid + 512] = st[1];
    dl[tid] = st[2];
    dl[tid + 512] = st[3];
  };

  uint u1[8], u2[8];
#pragma unroll
  for (int i = 0; i < 8; ++i) { u1[i] = 0xFFFFFFFFu; u2[i] = 0xFFFFFFFFu; }

  stage_load(0);
  stage_write(0);
  stage_load(1);
  __syncthreads();

  for (int c = 0; c < 8; ++c) {            // 8 chunks x 128 codes
    char* chb = (char*)&CS[c & 1][0][0];
    char* clb = (char*)&CS[c & 1][1][0];
#pragma unroll
    for (int ct = 0; ct < 8; ++ct) {
      int crow = ct * 16 + l15;            // code within chunk
      short8 bh[2], bl[2];
#pragma unroll
      for (int kk = 0; kk < 2; ++kk) {
        int byteoff = crow * 128 + ((((kk << 2) + lg) ^ (crow & 7)) << 4);
        bh[kk] = *(short8*)(chb + byteoff);
        bl[kk] = *(short8*)(clb + byteoff);
      }
      uint kidx = (uint)(c * 128 + crow);
      float cnv = CN[kidx];
#pragma unroll
      for (int rt = 0; rt < 2; ++rt) {
        f32x4 acc = {0.f, 0.f, 0.f, 0.f};
        acc = __builtin_amdgcn_mfma_f32_16x16x32_bf16(ah[rt][0], bh[0], acc, 0, 0, 0);
        acc = __builtin_amdgcn_mfma_f32_16x16x32_bf16(ah[rt][1], bh[1], acc, 0, 0, 0);
        acc = __builtin_amdgcn_mfma_f32_16x16x32_bf16(al[rt][0], bh[0], acc, 0, 0, 0);
        acc = __builtin_amdgcn_mfma_f32_16x16x32_bf16(al[rt][1], bh[1], acc, 0, 0, 0);
        acc = __builtin_amdgcn_mfma_f32_16x16x32_bf16(ah[rt][0], bl[0], acc, 0, 0, 0);
        acc = __builtin_amdgcn_mfma_f32_16x16x32_bf16(ah[rt][1], bl[1], acc, 0, 0, 0);
#pragma unroll
        for (int j = 0; j < 4; ++j) {
          float s = fmaf(-2.f, acc[j], cnv);        // 4096*score, in (0, 2^22)
          uint m = ((uint)s << 10) | kidx;          // fixed-point | index
          int slot = rt * 4 + j;
          uint t = max(u1[slot], m);
          u1[slot] = min(u1[slot], m);
          u2[slot] = min(u2[slot], t);
        }
      }
    }
    if (c < 7) {
      stage_write((c + 1) & 1);
      if (c < 6) stage_load(c + 2);
    }
    __syncthreads();
  }

  // ---- cross-lane top-2 merge over the 16 code-lanes; write packed best ----
#pragma unroll
  for (int rt = 0; rt < 2; ++rt) {
#pragma unroll
    for (int j = 0; j < 4; ++j) {
      int slot = rt * 4 + j;
      uint a1 = u1[slot], a2 = u2[slot];
#pragma unroll
      for (int off = 1; off < 16; off <<= 1) {
        uint o1 = (uint)__shfl_xor((int)a1, off);
        uint o2 = (uint)__shfl_xor((int)a2, off);
        a2 = min(min(a2, o2), max(a1, o1));
        a1 = min(a1, o1);
      }
      if (l15 == 0) {
        uint fl = ((a2 >> 10) - (a1 >> 10) < THR_Q) ? 0x80000000u : 0u;
        best[brow + wrow + rt * 16 + lg * 4 + j] =
            fl | ((a2 & 1023u) << 10) | (a1 & 1023u);
      }
    }
  }
}

// ---------------- fused: flagged-row exact check + quantize + counts ----------------
__global__ __launch_bounds__(256)
void nsvq_quant_count(const float* __restrict__ x,
                      const float* __restrict__ cb,
                      const float* __restrict__ rv,
                      const float* __restrict__ cn4k,
                      const uint* __restrict__ best,
                      int* __restrict__ counts,
                      float* __restrict__ out) {
  const int tid = threadIdx.x;
  const long row = (long)blockIdx.x * 16 + (tid >> 4);  // 16 rows/block, 16 lanes/row
  const int l = tid & 15;

  uint p = best[row];
  uint k = p & 1023u;
  float4 xv = ((const float4*)(x + row * NSVQ_D))[l];

  if (p & 0x80000000u) {
    uint k2 = (p >> 10) & 1023u;
    float4 a = ((const float4*)(cb + (long)k * NSVQ_D))[l];
    float4 b = ((const float4*)(cb + (long)k2 * NSVQ_D))[l];
    float d1 = xv.x * a.x + xv.y * a.y + xv.z * a.z + xv.w * a.w;
    float d2 = xv.x * b.x + xv.y * b.y + xv.z * b.z + xv.w * b.w;
#pragma unroll
    for (int off = 1; off < 16; off <<= 1) {
      d1 += __shfl_xor(d1, off, 64);
      d2 += __shfl_xor(d2, off, 64);
    }
    float s1 = fmaf(-8192.f, d1, cn4k[k]);   // 4096*score, exact fp32 dot
    float s2 = fmaf(-8192.f, d2, cn4k[k2]);
    if (s2 < s1 || (s2 == s1 && k2 < k)) k = k2;
  }

  float4 cv = ((const float4*)(cb + (long)k * NSVQ_D))[l];
  float4 rr = ((const float4*)(rv + row * NSVQ_D))[l];

  float dx = xv.x - cv.x, dy = xv.y - cv.y, dz = xv.z - cv.z, dw = xv.w - cv.w;
  float dres = dx * dx + dy * dy + dz * dz + dw * dw;
  float drnd = rr.x * rr.x + rr.y * rr.y + rr.z * rr.z + rr.w * rr.w;
#pragma unroll
  for (int off = 1; off < 16; off <<= 1) {
    dres += __shfl_xor(dres, off, 64);
    drnd += __shfl_xor(drnd, off, 64);
  }
  float scale = sqrtf(dres) / (sqrtf(drnd) + 1e-12f);

  float4 o;
  o.x = xv.x + scale * rr.x;
  o.y = xv.y + scale * rr.y;
  o.z = xv.z + scale * rr.z;
  o.w = xv.w + scale * rr.w;
  ((float4*)(out + row * NSVQ_D))[l] = o;

  if (l == 0) atomicAdd(&counts[k], 1);
}

// ---------------- perplexity + counts output ----------------
__global__ void nsvq_perp_kernel(const int* __restrict__ counts,
                                 float* __restrict__ out_tail,  // [0]=perp, [1..K]=counts
                                 float invN, int K) {
  int t = threadIdx.x;
  float v = 0.f;
  if (t < K) {
    int c = counts[t];
    out_tail[1 + t] = (float)c;
    float p = (float)c * invN;
    v = p * logf(p + 1e-12f);
  }
#pragma unroll
  for (int off = 1; off < 64; off <<= 1) v += __shfl_xor(v, off, 64);
  __shared__ float red[16];
  int wid = t >> 6;
  if ((t & 63) == 0) red[wid] = v;
  __syncthreads();
  if (t == 0) {
    float s = 0.f;
    int nw = (blockDim.x + 63) / 64;
    for (int w = 0; w < nw; ++w) s += red[w];
    out_tail[0] = expf(-s);
  }
}

extern "C" void kernel_launch(void* const* d_in, const int* in_sizes, int n_in,
                              void* d_out, int out_size, void* d_ws, size_t ws_size,
                              hipStream_t stream) {
  const float* x  = (const float*)d_in[0];
  const float* cb = (const float*)d_in[1];
  const float* rv = (const float*)d_in[2];
  float* out = (float*)d_out;

  const int D = NSVQ_D;
  const int N = in_sizes[0] / D;  // 131072
  const int K = in_sizes[1] / D;  // 1024

  float*  cn4k   = (float*)d_ws;
  int*    counts = (int*)((char*)d_ws + 4096);
  uint*   best   = (uint*)((char*)d_ws + 8192);
  ushort* cbh    = (ushort*)((char*)d_ws + 532480);
  ushort* cbl    = (ushort*)((char*)d_ws + 663552);

  nsvq_prep<<<(K + 255) / 256, 256, 0, stream>>>(cb, cbh, cbl, cn4k, counts, K);
  nsvq_argmin_mfma<<<N / ABN, 512, 0, stream>>>(x, cbh, cbl, cn4k, best);
  nsvq_quant_count<<<N / 16, 256, 0, stream>>>(x, cb, rv, cn4k, best, counts, out);
  nsvq_perp_kernel<<<1, 1024, 0, stream>>>(counts, out + (size_t)N * D, 1.0f / (float)N, K);
}

// Round 7
// 163.015 us; speedup vs baseline: 1.4068x; 1.4068x over previous
//
#include <hip/hip_runtime.h>
#include <math.h>

// NSVQ: N=131072 rows, D=64, K=1024 codes (fp32).
// out (flat f32): [0,N*D) quantized; [N*D] perplexity; [N*D+1,+K) counts.
// ws layout:
//   [0,4096)         cn4k   f32[K]     4096*(||c||^2 + 512)
//   [4096,8192)      counts int[K]
//   [8192,532480)    best   uint[N]    bit31=flag, bits10..19=k2, bits0..9=k1
//   [532480,663552)  cbh    ushort[K*64] bf16 hi, swizzled 16B blocks
//   [663552,794624)  cbl    ushort[K*64] bf16 lo, swizzled 16B blocks

#define NSVQ_D 64
#define ABN 256      // rows per argmin block (512 thr, 8 waves x 32 rows -> grid 512, 2 blocks/CU)
#define THR_Q 100u   // flag threshold in 1/4096 score quanta (~0.024)

typedef __attribute__((ext_vector_type(8))) short short8;
typedef __attribute__((ext_vector_type(4))) float f32x4;

__device__ __forceinline__ ushort bftrunc(float f) {
  return (ushort)(__float_as_uint(f) >> 16);
}
__device__ __forceinline__ float bf2f(ushort h) {
  return __uint_as_float(((uint)h) << 16);
}

// ---------------- prep: codebook norms + bf16 hi/lo split (swizzled) + zero counts ----------------
__global__ __launch_bounds__(256)
void nsvq_prep(const float* __restrict__ cb,
               ushort* __restrict__ cbh, ushort* __restrict__ cbl,
               float* __restrict__ cn4k, int* __restrict__ counts, int K) {
  if (blockIdx.x == 0) ((int4*)counts)[threadIdx.x] = make_int4(0, 0, 0, 0);
  int r = blockIdx.x * 256 + threadIdx.x;  // one code per thread
  if (r >= K) return;
  const float* row = cb + (long)r * NSVQ_D;
  float nrm = 0.f;
#pragma unroll
  for (int j = 0; j < 8; ++j) {            // dim block j = dims 8j..8j+7
    float4 v0 = *(const float4*)(row + j * 8);
    float4 v1 = *(const float4*)(row + j * 8 + 4);
    float f[8] = {v0.x, v0.y, v0.z, v0.w, v1.x, v1.y, v1.z, v1.w};
    ushort h[8], l[8];
#pragma unroll
    for (int e = 0; e < 8; ++e) {
      nrm = fmaf(f[e], f[e], nrm);
      ushort hb = bftrunc(f[e]);
      h[e] = hb;
      l[e] = bftrunc(f[e] - bf2f(hb));
    }
    int blk = r * 8 + (j ^ (r & 7));       // swizzled 16B block index
    *(uint4*)(cbh + blk * 8) = *(uint4*)h;
    *(uint4*)(cbl + blk * 8) = *(uint4*)l;
  }
  cn4k[r] = 4096.f * (nrm + 512.f);        // offset keeps scores in (0, 2^22)
}

// ---------------- MFMA argmin: 256 rows/block, 8 waves, fixed-point packed top-2 ----------------
// NOTE: 2nd launch_bounds arg behaves like CUDA min-blocks/CU on this hipcc:
// (512,4) capped VGPR at 64 -> catastrophic spill (R6: 279MB scratch fetch).
// (512,2) -> VGPR 128, no spill (R5-verified), 2 blocks/CU co-resident.
__global__ __launch_bounds__(512, 2)
void nsvq_argmin_mfma(const float* __restrict__ x,
                      const ushort* __restrict__ cbh,
                      const ushort* __restrict__ cbl,
                      const float* __restrict__ cn4k,
                      uint* __restrict__ best) {
  __shared__ ushort CS[2][2][128 * 64];    // [buf][hi/lo][code*64], 64 KB, swizzled
  __shared__ float CN[1024];               // 4 KB: cn4k resident in LDS
  const int tid = threadIdx.x;
  const int lane = tid & 63;
  const int wid = tid >> 6;                // 0..7, each wave owns 32 rows
  const int l15 = lane & 15;
  const int lg = lane >> 4;                // 0..3
  const long brow = (long)blockIdx.x * ABN;
  const int wrow = wid * 32;

  CN[tid] = cn4k[tid];
  CN[tid + 512] = cn4k[tid + 512];

  // ---- A fragments (X rows scaled by 4096), bf16 hi/lo, register-resident ----
  short8 ah[2][2], al[2][2];
#pragma unroll
  for (int rt = 0; rt < 2; ++rt) {
#pragma unroll
    for (int kk = 0; kk < 2; ++kk) {
      const float* xr = x + (brow + wrow + rt * 16 + l15) * NSVQ_D + kk * 32 + lg * 8;
      float4 v0 = *(const float4*)xr;
      float4 v1 = *(const float4*)(xr + 4);
      float f[8] = {v0.x, v0.y, v0.z, v0.w, v1.x, v1.y, v1.z, v1.w};
      short8 h, lo;
#pragma unroll
      for (int j = 0; j < 8; ++j) {
        float fs = f[j] * 4096.f;          // exact power-of-2 scale
        ushort hb = bftrunc(fs);
        h[j] = (short)hb;
        lo[j] = (short)bftrunc(fs - bf2f(hb));
      }
      ah[rt][kk] = h;
      al[rt][kk] = lo;
    }
  }

  // ---- linear chunk staging (pre-swizzled in ws): 32 KB per chunk ----
  uint4 st[4];
  auto stage_load = [&](int c) {
    const uint4* ph = (const uint4*)cbh + c * 1024;
    const uint4* pl = (const uint4*)cbl + c * 1024;
    st[0] = ph[tid];
    st[1] = ph[tid + 512];
    st[2] = pl[tid];
    st[3] = pl[tid + 512];
  };
  auto stage_write = [&](int b) {
    uint4* dh = (uint4*)&CS[b][0][0];
    uint4* dl = (uint4*)&CS[b][1][0];
    dh[tid] = st[0];
    dh[tid + 512] = st[1];
    dl[tid] = st[2];
    dl[tid + 512] = st[3];
  };

  uint u1[8], u2[8];
#pragma unroll
  for (int i = 0; i < 8; ++i) { u1[i] = 0xFFFFFFFFu; u2[i] = 0xFFFFFFFFu; }

  stage_load(0);
  stage_write(0);
  stage_load(1);
  __syncthreads();

  for (int c = 0; c < 8; ++c) {            // 8 chunks x 128 codes
    char* chb = (char*)&CS[c & 1][0][0];
    char* clb = (char*)&CS[c & 1][1][0];
#pragma unroll
    for (int ct = 0; ct < 8; ++ct) {
      int crow = ct * 16 + l15;            // code within chunk
      short8 bh[2], bl[2];
#pragma unroll
      for (int kk = 0; kk < 2; ++kk) {
        int byteoff = crow * 128 + ((((kk << 2) + lg) ^ (crow & 7)) << 4);
        bh[kk] = *(short8*)(chb + byteoff);
        bl[kk] = *(short8*)(clb + byteoff);
      }
      uint kidx = (uint)(c * 128 + crow);
      float cnv = CN[kidx];
#pragma unroll
      for (int rt = 0; rt < 2; ++rt) {
        f32x4 acc = {0.f, 0.f, 0.f, 0.f};
        acc = __builtin_amdgcn_mfma_f32_16x16x32_bf16(ah[rt][0], bh[0], acc, 0, 0, 0);
        acc = __builtin_amdgcn_mfma_f32_16x16x32_bf16(ah[rt][1], bh[1], acc, 0, 0, 0);
        acc = __builtin_amdgcn_mfma_f32_16x16x32_bf16(al[rt][0], bh[0], acc, 0, 0, 0);
        acc = __builtin_amdgcn_mfma_f32_16x16x32_bf16(al[rt][1], bh[1], acc, 0, 0, 0);
        acc = __builtin_amdgcn_mfma_f32_16x16x32_bf16(ah[rt][0], bl[0], acc, 0, 0, 0);
        acc = __builtin_amdgcn_mfma_f32_16x16x32_bf16(ah[rt][1], bl[1], acc, 0, 0, 0);
#pragma unroll
        for (int j = 0; j < 4; ++j) {
          float s = fmaf(-2.f, acc[j], cnv);        // 4096*score, in (0, 2^22)
          uint m = ((uint)s << 10) | kidx;          // fixed-point | index
          int slot = rt * 4 + j;
          uint t = max(u1[slot], m);
          u1[slot] = min(u1[slot], m);
          u2[slot] = min(u2[slot], t);
        }
      }
    }
    if (c < 7) {
      stage_write((c + 1) & 1);
      if (c < 6) stage_load(c + 2);
    }
    __syncthreads();
  }

  // ---- cross-lane top-2 merge over the 16 code-lanes; write packed best ----
#pragma unroll
  for (int rt = 0; rt < 2; ++rt) {
#pragma unroll
    for (int j = 0; j < 4; ++j) {
      int slot = rt * 4 + j;
      uint a1 = u1[slot], a2 = u2[slot];
#pragma unroll
      for (int off = 1; off < 16; off <<= 1) {
        uint o1 = (uint)__shfl_xor((int)a1, off);
        uint o2 = (uint)__shfl_xor((int)a2, off);
        a2 = min(min(a2, o2), max(a1, o1));
        a1 = min(a1, o1);
      }
      if (l15 == 0) {
        uint fl = ((a2 >> 10) - (a1 >> 10) < THR_Q) ? 0x80000000u : 0u;
        best[brow + wrow + rt * 16 + lg * 4 + j] =
            fl | ((a2 & 1023u) << 10) | (a1 & 1023u);
      }
    }
  }
}

// ---------------- fused: flagged-row exact check + quantize + counts ----------------
__global__ __launch_bounds__(256)
void nsvq_quant_count(const float* __restrict__ x,
                      const float* __restrict__ cb,
                      const float* __restrict__ rv,
                      const float* __restrict__ cn4k,
                      const uint* __restrict__ best,
                      int* __restrict__ counts,
                      float* __restrict__ out) {
  const int tid = threadIdx.x;
  const long row = (long)blockIdx.x * 16 + (tid >> 4);  // 16 rows/block, 16 lanes/row
  const int l = tid & 15;

  uint p = best[row];
  uint k = p & 1023u;
  float4 xv = ((const float4*)(x + row * NSVQ_D))[l];

  if (p & 0x80000000u) {
    uint k2 = (p >> 10) & 1023u;
    float4 a = ((const float4*)(cb + (long)k * NSVQ_D))[l];
    float4 b = ((const float4*)(cb + (long)k2 * NSVQ_D))[l];
    float d1 = xv.x * a.x + xv.y * a.y + xv.z * a.z + xv.w * a.w;
    float d2 = xv.x * b.x + xv.y * b.y + xv.z * b.z + xv.w * b.w;
#pragma unroll
    for (int off = 1; off < 16; off <<= 1) {
      d1 += __shfl_xor(d1, off, 64);
      d2 += __shfl_xor(d2, off, 64);
    }
    float s1 = fmaf(-8192.f, d1, cn4k[k]);   // 4096*score, exact fp32 dot
    float s2 = fmaf(-8192.f, d2, cn4k[k2]);
    if (s2 < s1 || (s2 == s1 && k2 < k)) k = k2;
  }

  float4 cv = ((const float4*)(cb + (long)k * NSVQ_D))[l];
  float4 rr = ((const float4*)(rv + row * NSVQ_D))[l];

  float dx = xv.x - cv.x, dy = xv.y - cv.y, dz = xv.z - cv.z, dw = xv.w - cv.w;
  float dres = dx * dx + dy * dy + dz * dz + dw * dw;
  float drnd = rr.x * rr.x + rr.y * rr.y + rr.z * rr.z + rr.w * rr.w;
#pragma unroll
  for (int off = 1; off < 16; off <<= 1) {
    dres += __shfl_xor(dres, off, 64);
    drnd += __shfl_xor(drnd, off, 64);
  }
  float scale = sqrtf(dres) / (sqrtf(drnd) + 1e-12f);

  float4 o;
  o.x = xv.x + scale * rr.x;
  o.y = xv.y + scale * rr.y;
  o.z = xv.z + scale * rr.z;
  o.w = xv.w + scale * rr.w;
  ((float4*)(out + row * NSVQ_D))[l] = o;

  if (l == 0) atomicAdd(&counts[k], 1);
}

// ---------------- perplexity + counts output ----------------
__global__ void nsvq_perp_kernel(const int* __restrict__ counts,
                                 float* __restrict__ out_tail,  // [0]=perp, [1..K]=counts
                                 float invN, int K) {
  int t = threadIdx.x;
  float v = 0.f;
  if (t < K) {
    int c = counts[t];
    out_tail[1 + t] = (float)c;
    float p = (float)c * invN;
    v = p * logf(p + 1e-12f);
  }
#pragma unroll
  for (int off = 1; off < 64; off <<= 1) v += __shfl_xor(v, off, 64);
  __shared__ float red[16];
  int wid = t >> 6;
  if ((t & 63) == 0) red[wid] = v;
  __syncthreads();
  if (t == 0) {
    float s = 0.f;
    int nw = (blockDim.x + 63) / 64;
    for (int w = 0; w < nw; ++w) s += red[w];
    out_tail[0] = expf(-s);
  }
}

extern "C" void kernel_launch(void* const* d_in, const int* in_sizes, int n_in,
                              void* d_out, int out_size, void* d_ws, size_t ws_size,
                              hipStream_t stream) {
  const float* x  = (const float*)d_in[0];
  const float* cb = (const float*)d_in[1];
  const float* rv = (const float*)d_in[2];
  float* out = (float*)d_out;

  const int D = NSVQ_D;
  const int N = in_sizes[0] / D;  // 131072
  const int K = in_sizes[1] / D;  // 1024

  float*  cn4k   = (float*)d_ws;
  int*    counts = (int*)((char*)d_ws + 4096);
  uint*   best   = (uint*)((char*)d_ws + 8192);
  ushort* cbh    = (ushort*)((char*)d_ws + 532480);
  ushort* cbl    = (ushort*)((char*)d_ws + 663552);

  nsvq_prep<<<(K + 255) / 256, 256, 0, stream>>>(cb, cbh, cbl, cn4k, counts, K);
  nsvq_argmin_mfma<<<N / ABN, 512, 0, stream>>>(x, cbh, cbl, cn4k, best);
  nsvq_quant_count<<<N / 16, 256, 0, stream>>>(x, cb, rv, cn4k, best, counts, out);
  nsvq_perp_kernel<<<1, 1024, 0, stream>>>(counts, out + (size_t)N * D, 1.0f / (float)N, K);
}

// Round 8
// 117.335 us; speedup vs baseline: 1.9545x; 1.3893x over previous
//
#include <hip/hip_runtime.h>
#include <math.h>

// NSVQ: N=131072 rows, D=64, K=1024 codes (fp32).
// out (flat f32): [0,N*D) quantized; [N*D] perplexity; [N*D+1,+K) counts.
// ws layout:
//   [0,4096)         cn2k   f32[K]     2048*(||c||^2 + 512)
//   [4096,8192)      counts int[K]
//   [8192,532480)    best   uint[N]    bit31=flag, bits10..19=k2, bits0..9=k1
//   [532480,663552)  cbh    ushort[K*64] bf16 hi, swizzled 16B blocks
//   [663552,794624)  cbl    ushort[K*64] bf16 lo, swizzled 16B blocks

#define NSVQ_D 64
#define ABN 256     // rows per argmin block (512 thr, 8 waves x 32 rows -> grid 512)
#define THR_Q 50u   // flag threshold in 1/2048 score quanta (~0.024); err bound ~7 quanta

typedef __attribute__((ext_vector_type(8))) short short8;
typedef __attribute__((ext_vector_type(4))) float f32x4;

__device__ __forceinline__ ushort bftrunc(float f) {
  return (ushort)(__float_as_uint(f) >> 16);
}
__device__ __forceinline__ float bf2f(ushort h) {
  return __uint_as_float(((uint)h) << 16);
}

// ---------------- prep: codebook norms + bf16 hi/lo split (swizzled) + zero counts ----------------
__global__ __launch_bounds__(256)
void nsvq_prep(const float* __restrict__ cb,
               ushort* __restrict__ cbh, ushort* __restrict__ cbl,
               float* __restrict__ cn2k, int* __restrict__ counts, int K) {
  if (blockIdx.x == 0) ((int4*)counts)[threadIdx.x] = make_int4(0, 0, 0, 0);
  int r = blockIdx.x * 256 + threadIdx.x;  // one code per thread
  if (r >= K) return;
  const float* row = cb + (long)r * NSVQ_D;
  float nrm = 0.f;
#pragma unroll
  for (int j = 0; j < 8; ++j) {            // dim block j = dims 8j..8j+7
    float4 v0 = *(const float4*)(row + j * 8);
    float4 v1 = *(const float4*)(row + j * 8 + 4);
    float f[8] = {v0.x, v0.y, v0.z, v0.w, v1.x, v1.y, v1.z, v1.w};
    ushort h[8], l[8];
#pragma unroll
    for (int e = 0; e < 8; ++e) {
      nrm = fmaf(f[e], f[e], nrm);
      ushort hb = bftrunc(f[e]);
      h[e] = hb;
      l[e] = bftrunc(f[e] - bf2f(hb));
    }
    int blk = r * 8 + (j ^ (r & 7));       // swizzled 16B block index
    *(uint4*)(cbh + blk * 8) = *(uint4*)h;
    *(uint4*)(cbl + blk * 8) = *(uint4*)l;
  }
  cn2k[r] = 2048.f * (nrm + 512.f);        // acc-init constant; keeps scores in (0, 2^21)
}

// ---------------- MFMA argmin: 256 rows/block, 8 waves, fixed-point packed top-2 ----------------
// launch_bounds 2nd arg = min blocks/CU on this hipcc: (512,4) capped VGPR at 64 ->
// catastrophic spill (R6). (512,2) -> cap 128, no spill (R5/R7-verified).
__global__ __launch_bounds__(512, 2)
void nsvq_argmin_mfma(const float* __restrict__ x,
                      const ushort* __restrict__ cbh,
                      const ushort* __restrict__ cbl,
                      const float* __restrict__ cn2k,
                      uint* __restrict__ best) {
  __shared__ ushort CS[2][2][128 * 64];    // exactly 64 KB -> two blocks/CU fit
  const int tid = threadIdx.x;
  const int lane = tid & 63;
  const int wid = tid >> 6;                // 0..7, each wave owns 32 rows
  const int l15 = lane & 15;
  const int lg = lane >> 4;                // 0..3
  const long brow = (long)blockIdx.x * ABN;
  const int wrow = wid * 32;

  // ---- A fragments (X rows scaled by -4096), bf16 hi/lo, register-resident ----
  short8 ah[2][2], al[2][2];
#pragma unroll
  for (int rt = 0; rt < 2; ++rt) {
#pragma unroll
    for (int kk = 0; kk < 2; ++kk) {
      const float* xr = x + (brow + wrow + rt * 16 + l15) * NSVQ_D + kk * 32 + lg * 8;
      float4 v0 = *(const float4*)xr;
      float4 v1 = *(const float4*)(xr + 4);
      float f[8] = {v0.x, v0.y, v0.z, v0.w, v1.x, v1.y, v1.z, v1.w};
      short8 h, lo;
#pragma unroll
      for (int j = 0; j < 8; ++j) {
        float fs = f[j] * -4096.f;         // exact power-of-2 scale; -2*2048 folded in
        ushort hb = bftrunc(fs);
        h[j] = (short)hb;
        lo[j] = (short)bftrunc(fs - bf2f(hb));
      }
      ah[rt][kk] = h;
      al[rt][kk] = lo;
    }
  }

  // ---- linear chunk staging (pre-swizzled in ws): 32 KB per chunk ----
  uint4 st[4];
  auto stage_load = [&](int c) {
    const uint4* ph = (const uint4*)cbh + c * 1024;
    const uint4* pl = (const uint4*)cbl + c * 1024;
    st[0] = ph[tid];
    st[1] = ph[tid + 512];
    st[2] = pl[tid];
    st[3] = pl[tid + 512];
  };
  auto stage_write = [&](int b) {
    uint4* dh = (uint4*)&CS[b][0][0];
    uint4* dl = (uint4*)&CS[b][1][0];
    dh[tid] = st[0];
    dh[tid + 512] = st[1];
    dl[tid] = st[2];
    dl[tid + 512] = st[3];
  };

  uint u1[8], u2[8];
#pragma unroll
  for (int i = 0; i < 8; ++i) { u1[i] = 0xFFFFFFFFu; u2[i] = 0xFFFFFFFFu; }

  stage_load(0);
  stage_write(0);
  stage_load(1);
  __syncthreads();

  for (int c = 0; c < 8; ++c) {            // 8 chunks x 128 codes
    // stage-early: LDS-write next chunk, issue loads for chunk+2, THEN compute.
    // Loads get the whole compute phase to land -> barrier vmcnt drain ~free.
    if (c < 7) stage_write((c + 1) & 1);
    if (c < 6) stage_load(c + 2);
    char* chb = (char*)&CS[c & 1][0][0];
    char* clb = (char*)&CS[c & 1][1][0];

    float cnvv[8];                         // prefetch cn for this chunk (L1-hot, 4 KB)
#pragma unroll
    for (int q = 0; q < 8; ++q)
      cnvv[q] = cn2k[c * 128 + (((q + wid) & 7) << 4) + l15];

#pragma unroll
    for (int ct0 = 0; ct0 < 8; ++ct0) {
      const int ct = (ct0 + wid) & 7;      // per-wave stagger: desync pipes across waves
      const int crow = (ct << 4) + l15;
      short8 bh[2], bl[2];
#pragma unroll
      for (int kk = 0; kk < 2; ++kk) {
        int byteoff = crow * 128 + ((((kk << 2) + lg) ^ (crow & 7)) << 4);
        bh[kk] = *(short8*)(chb + byteoff);
        bl[kk] = *(short8*)(clb + byteoff);
      }
      const uint kidx = (uint)(c * 128 + crow);
      const float cnv = cnvv[ct0];
#pragma unroll
      for (int rt = 0; rt < 2; ++rt) {
        f32x4 acc = {cnv, cnv, cnv, cnv};  // ||c||^2-term pre-loaded into accumulator
        __builtin_amdgcn_s_setprio(1);
        acc = __builtin_amdgcn_mfma_f32_16x16x32_bf16(ah[rt][0], bh[0], acc, 0, 0, 0);
        acc = __builtin_amdgcn_mfma_f32_16x16x32_bf16(ah[rt][1], bh[1], acc, 0, 0, 0);
        acc = __builtin_amdgcn_mfma_f32_16x16x32_bf16(al[rt][0], bh[0], acc, 0, 0, 0);
        acc = __builtin_amdgcn_mfma_f32_16x16x32_bf16(al[rt][1], bh[1], acc, 0, 0, 0);
        acc = __builtin_amdgcn_mfma_f32_16x16x32_bf16(ah[rt][0], bl[0], acc, 0, 0, 0);
        acc = __builtin_amdgcn_mfma_f32_16x16x32_bf16(ah[rt][1], bl[1], acc, 0, 0, 0);
        __builtin_amdgcn_s_setprio(0);
#pragma unroll
        for (int j = 0; j < 4; ++j) {      // acc IS 2048*score (>0, <2^21)
          uint m = ((uint)acc[j] << 10) | kidx;
          int slot = rt * 4 + j;
          uint t = max(u1[slot], m);
          u1[slot] = min(u1[slot], m);
          u2[slot] = min(u2[slot], t);
        }
      }
    }
    __syncthreads();
  }

  // ---- cross-lane top-2 merge over the 16 code-lanes; write packed best ----
#pragma unroll
  for (int rt = 0; rt < 2; ++rt) {
#pragma unroll
    for (int j = 0; j < 4; ++j) {
      int slot = rt * 4 + j;
      uint a1 = u1[slot], a2 = u2[slot];
#pragma unroll
      for (int off = 1; off < 16; off <<= 1) {
        uint o1 = (uint)__shfl_xor((int)a1, off);
        uint o2 = (uint)__shfl_xor((int)a2, off);
        a2 = min(min(a2, o2), max(a1, o1));
        a1 = min(a1, o1);
      }
      if (l15 == 0) {
        uint fl = ((a2 >> 10) - (a1 >> 10) < THR_Q) ? 0x80000000u : 0u;
        best[brow + wrow + rt * 16 + lg * 4 + j] =
            fl | ((a2 & 1023u) << 10) | (a1 & 1023u);
      }
    }
  }
}

// ---------------- cleanup: per-thread top-2 exact check + counts histogram ----------------
__global__ __launch_bounds__(256)
void nsvq_cleanup(const float* __restrict__ x,
                  const float* __restrict__ cb,
                  const float* __restrict__ cn2k,
                  uint* __restrict__ best,
                  int* __restrict__ counts) {
  __shared__ int hist[1024];
#pragma unroll
  for (int i = threadIdx.x; i < 1024; i += 256) hist[i] = 0;
  __syncthreads();

  const long row = (long)blockIdx.x * 256 + threadIdx.x;
  uint p = best[row];
  uint k = p & 1023u;
  if (p & 0x80000000u) {
    uint k2 = (p >> 10) & 1023u;
    const float4* xr = (const float4*)(x + row * NSVQ_D);
    const float4* c1 = (const float4*)(cb + (long)k * NSVQ_D);
    const float4* c2 = (const float4*)(cb + (long)k2 * NSVQ_D);
    float d1 = 0.f, d2 = 0.f;
#pragma unroll
    for (int q = 0; q < 16; ++q) {
      float4 xv = xr[q], a = c1[q], b = c2[q];
      d1 = fmaf(xv.x, a.x, d1); d1 = fmaf(xv.y, a.y, d1);
      d1 = fmaf(xv.z, a.z, d1); d1 = fmaf(xv.w, a.w, d1);
      d2 = fmaf(xv.x, b.x, d2); d2 = fmaf(xv.y, b.y, d2);
      d2 = fmaf(xv.z, b.z, d2); d2 = fmaf(xv.w, b.w, d2);
    }
    float s1 = fmaf(-4096.f, d1, cn2k[k]);   // 2048*score, exact fp32 dot
    float s2 = fmaf(-4096.f, d2, cn2k[k2]);
    if (s2 < s1 || (s2 == s1 && k2 < k)) k = k2;
    best[row] = k;                            // clean entry for epilogue
  }
  atomicAdd(&hist[k], 1);
  __syncthreads();
  for (int i = threadIdx.x; i < 1024; i += 256) {
    int v = hist[i];
    if (v) atomicAdd(&counts[i], v);
  }
}

// ---------------- epilogue: noise-substitution quantization ----------------
__global__ __launch_bounds__(256)
void nsvq_epilogue_kernel(const float* __restrict__ x,
                          const float* __restrict__ cb,
                          const float* __restrict__ rv,
                          const uint* __restrict__ best,
                          float* __restrict__ out) {
  const int tid = threadIdx.x;
  const long row = (long)blockIdx.x * 16 + (tid >> 4);
  const int l = tid & 15;
  const int k = (int)(best[row] & 1023u);

  float4 xv = ((const float4*)(x + row * NSVQ_D))[l];
  float4 cv = ((const float4*)(cb + (long)k * NSVQ_D))[l];
  float4 rr = ((const float4*)(rv + row * NSVQ_D))[l];

  float dx = xv.x - cv.x, dy = xv.y - cv.y, dz = xv.z - cv.z, dw = xv.w - cv.w;
  float dres = dx * dx + dy * dy + dz * dz + dw * dw;
  float drnd = rr.x * rr.x + rr.y * rr.y + rr.z * rr.z + rr.w * rr.w;
#pragma unroll
  for (int off = 1; off < 16; off <<= 1) {
    dres += __shfl_xor(dres, off, 64);
    drnd += __shfl_xor(drnd, off, 64);
  }
  float scale = sqrtf(dres) / (sqrtf(drnd) + 1e-12f);

  float4 o;
  o.x = xv.x + scale * rr.x;
  o.y = xv.y + scale * rr.y;
  o.z = xv.z + scale * rr.z;
  o.w = xv.w + scale * rr.w;
  ((float4*)(out + row * NSVQ_D))[l] = o;
}

// ---------------- perplexity + counts output ----------------
__global__ void nsvq_perp_kernel(const int* __restrict__ counts,
                                 float* __restrict__ out_tail,  // [0]=perp, [1..K]=counts
                                 float invN, int K) {
  int t = threadIdx.x;
  float v = 0.f;
  if (t < K) {
    int c = counts[t];
    out_tail[1 + t] = (float)c;
    float p = (float)c * invN;
    v = p * logf(p + 1e-12f);
  }
#pragma unroll
  for (int off = 1; off < 64; off <<= 1) v += __shfl_xor(v, off, 64);
  __shared__ float red[16];
  int wid = t >> 6;
  if ((t & 63) == 0) red[wid] = v;
  __syncthreads();
  if (t == 0) {
    float s = 0.f;
    int nw = (blockDim.x + 63) / 64;
    for (int w = 0; w < nw; ++w) s += red[w];
    out_tail[0] = expf(-s);
  }
}

extern "C" void kernel_launch(void* const* d_in, const int* in_sizes, int n_in,
                              void* d_out, int out_size, void* d_ws, size_t ws_size,
                              hipStream_t stream) {
  const float* x  = (const float*)d_in[0];
  const float* cb = (const float*)d_in[1];
  const float* rv = (const float*)d_in[2];
  float* out = (float*)d_out;

  const int D = NSVQ_D;
  const int N = in_sizes[0] / D;  // 131072
  const int K = in_sizes[1] / D;  // 1024

  float*  cn2k   = (float*)d_ws;
  int*    counts = (int*)((char*)d_ws + 4096);
  uint*   best   = (uint*)((char*)d_ws + 8192);
  ushort* cbh    = (ushort*)((char*)d_ws + 532480);
  ushort* cbl    = (ushort*)((char*)d_ws + 663552);

  nsvq_prep<<<(K + 255) / 256, 256, 0, stream>>>(cb, cbh, cbl, cn2k, counts, K);
  nsvq_argmin_mfma<<<N / ABN, 512, 0, stream>>>(x, cbh, cbl, cn2k, best);
  nsvq_cleanup<<<N / 256, 256, 0, stream>>>(x, cb, cn2k, best, counts);
  nsvq_epilogue_kernel<<<N / 16, 256, 0, stream>>>(x, cb, rv, best, out);
  nsvq_perp_kernel<<<1, 1024, 0, stream>>>(counts, out + (size_t)N * D, 1.0f / (float)N, K);
}